// Round 6
// baseline (493.420 us; speedup 1.0000x reference)
//
#include <hip/hip_runtime.h>
#include <hip/hip_bf16.h>
#include <stdint.h>

#define D 1024
#define NSUP 256
#define ROWS 16384      // 4*4096
#define MB 64           // rows per block
#define LTHREADS 1024   // 16 waves
#define LGRID (ROWS / MB)   // 256 blocks = 1/CU
#define LDS_BYTES 163840    // h 128K + wbuf 32K

typedef __attribute__((__ext_vector_type__(8))) __bf16 bf16x8;
typedef __attribute__((__ext_vector_type__(4))) float f32x4;

#define MFMA16(a, b, c) __builtin_amdgcn_mfma_f32_16x16x32_bf16((a), (b), (c), 0, 0, 0)

__global__ void cast_k_kernel(const float* __restrict__ K, __bf16* __restrict__ Kb) {
    int i = (blockIdx.x * 256 + threadIdx.x) * 4;
    float4 v = *(const float4*)(K + i);
    __bf16 o[4] __attribute__((aligned(8)));
    o[0] = (__bf16)v.x; o[1] = (__bf16)v.y; o[2] = (__bf16)v.z; o[3] = (__bf16)v.w;
    *(uint2*)(Kb + i) = *(const uint2*)o;
}

// V [4][256][1024] f32 -> Vt [4][1024][256] bf16
__global__ void transpose_v_kernel(const float* __restrict__ V, __bf16* __restrict__ Vt) {
    __shared__ __bf16 tile[64][72];
    int l = blockIdx.z;
    int d0 = blockIdx.x * 64, n0 = blockIdx.y * 64;
    const float* Vl = V + (size_t)l * NSUP * D;
    __bf16* Vtl = Vt + (size_t)l * D * NSUP;
    for (int j = 0; j < 16; ++j) {
        int idx = j * 256 + threadIdx.x;
        int n_l = idx >> 6, d_l = idx & 63;
        tile[d_l][n_l] = (__bf16)Vl[(size_t)(n0 + n_l) * D + d0 + d_l];
    }
    __syncthreads();
    for (int j = 0; j < 16; ++j) {
        int idx = j * 256 + threadIdx.x;
        int d_l = idx >> 6, n_l = idx & 63;
        Vtl[(size_t)(d0 + d_l) * NSUP + n0 + n_l] = tile[d_l][n_l];
    }
}

// All 4 layers fused, h resident in LDS (raw bf16, swizzled).
// Per layer: [sqp store | karr preload | A-MFMA] bar1 [rn, exp, exp-partials]
// bar2 [S totals, w->wbuf] bar3 [varr preload | C-MFMA | raw-h writeback] bar4.
// No softmax max-pass: |score*rn| <= |k_row| ~ 34 -> exp2 arg <= 49, f32-safe.
__global__ __launch_bounds__(LTHREADS, 4)
void fused4_kernel(const float* __restrict__ x, float* __restrict__ out,
                   const __bf16* __restrict__ Kb, const __bf16* __restrict__ Vt) {
    extern __shared__ __align__(16) char pool[];
    char* wbuf = pool + 131072;
    const int tid = threadIdx.x;
    const int lane = tid & 63;
    const int wv = tid >> 6;            // wave 0..15
    const int llo = lane & 15, lhi = lane >> 4;
    const int swzk = (llo & 7) << 4;    // swizzle key for row = *16 + llo
    const int row0 = blockIdx.x * MB;

    // ---- stage x -> raw bf16 h (swizzled) + layer-0 rn ----
    {
        const int srow = tid >> 4, c16 = tid & 15;
        const float* xr = x + (size_t)(row0 + srow) * D;
        const int sk = (srow & 7) << 4;
        float ss = 0.f;
        #pragma unroll
        for (int q = 0; q < 16; ++q) {
            float4 v = *(const float4*)(xr + (c16 + q * 16) * 4);
            ss += v.x * v.x + v.y * v.y + v.z * v.z + v.w * v.w;
            __bf16 t[4] __attribute__((aligned(8)));
            t[0] = (__bf16)v.x; t[1] = (__bf16)v.y; t[2] = (__bf16)v.z; t[3] = (__bf16)v.w;
            *(uint2*)(pool + srow * 2048 + (((c16 + q * 16) * 8) ^ sk)) = *(const uint2*)t;
        }
        ss += __shfl_xor(ss, 1); ss += __shfl_xor(ss, 2);
        ss += __shfl_xor(ss, 4); ss += __shfl_xor(ss, 8);
        if (c16 == 0) *(float*)(wbuf + srow * 4) = 1.f / (sqrtf(ss) + 1e-9f);
    }
    __syncthreads();

    float sqp[4][4];   // prev-layer |row|^2 partials (valid for l>0)

    #pragma unroll 1
    for (int l = 0; l < 4; ++l) {
        // ---- previous layer's sq-norm partials -> wbuf[0:4K) (wbuf is dead here) ----
        if (l > 0) {
            #pragma unroll
            for (int rf = 0; rf < 4; ++rf)
                #pragma unroll
                for (int r = 0; r < 4; ++r)
                    if (llo == 0)
                        *(float*)(wbuf + (rf * 16 + lhi * 4 + r) * 64 + wv * 4) = sqp[rf][r];
        }

        // ---- K slice -> registers (coalesced batch; pipelines L2 latency) ----
        bf16x8 karr[32];
        const __bf16* kb0 = Kb + (size_t)l * NSUP * D + (size_t)(wv * 16 + llo) * D + lhi * 8;
        #pragma unroll
        for (int k = 0; k < 32; ++k) karr[k] = *(const bf16x8*)(kb0 + k * 32);

        // ---- Phase A: scores[64x256] = h @ K^T; wave owns cols [wv*16,+16) ----
        f32x4 acc[4];
        #pragma unroll
        for (int rf = 0; rf < 4; ++rf) acc[rf] = (f32x4){0.f, 0.f, 0.f, 0.f};
        #pragma unroll
        for (int k = 0; k < 32; ++k) {
            #pragma unroll
            for (int rf = 0; rf < 4; ++rf) {
                bf16x8 a = *(const bf16x8*)(pool + (rf * 16 + llo) * 2048 + ((k * 64 + lhi * 16) ^ swzk));
                acc[rf] = MFMA16(a, karr[k], acc[rf]);
            }
        }
        __syncthreads();   // bar1: A done; h + wbuf red partials readable

        // ---- rn for this layer ----
        float rnv[4][4];
        if (l == 0) {
            #pragma unroll
            for (int rf = 0; rf < 4; ++rf)
                #pragma unroll
                for (int r = 0; r < 4; ++r)
                    rnv[rf][r] = *(const float*)(wbuf + (rf * 16 + lhi * 4 + r) * 4);
        } else {
            #pragma unroll
            for (int rf = 0; rf < 4; ++rf)
                #pragma unroll
                for (int r = 0; r < 4; ++r) {
                    const f32x4* rp = (const f32x4*)(wbuf + (rf * 16 + lhi * 4 + r) * 64);
                    f32x4 s0 = rp[0], s1 = rp[1], s2 = rp[2], s3 = rp[3];
                    float ss = (s0[0] + s0[1] + s0[2] + s0[3]) + (s1[0] + s1[1] + s1[2] + s1[3])
                             + (s2[0] + s2[1] + s2[2] + s2[3]) + (s3[0] + s3[1] + s3[2] + s3[3]);
                    rnv[rf][r] = 1.f / (sqrtf(ss) + 1e-9f);
                }
        }

        // ---- exp (no max-sub) + partial sums -> pool[0:4K) (h rows 0-1 dead) ----
        float ee[4][4];
        #pragma unroll
        for (int rf = 0; rf < 4; ++rf)
            #pragma unroll
            for (int r = 0; r < 4; ++r) {
                float e = exp2f(acc[rf][r] * rnv[rf][r] * 1.44269504f);
                ee[rf][r] = e;
                float s = e;
                s += __shfl_xor(s, 1); s += __shfl_xor(s, 2);
                s += __shfl_xor(s, 4); s += __shfl_xor(s, 8);
                if (llo == 0) *(float*)(pool + (rf * 16 + lhi * 4 + r) * 64 + wv * 4) = s;
            }
        __syncthreads();   // bar2: exp partials visible

        #pragma unroll
        for (int rf = 0; rf < 4; ++rf)
            #pragma unroll
            for (int r = 0; r < 4; ++r) {
                int row = rf * 16 + lhi * 4 + r;
                const f32x4* rp = (const f32x4*)(pool + row * 64);
                f32x4 s0 = rp[0], s1 = rp[1], s2 = rp[2], s3 = rp[3];
                float S = (s0[0] + s0[1] + s0[2] + s0[3]) + (s1[0] + s1[1] + s1[2] + s1[3])
                        + (s2[0] + s2[1] + s2[2] + s2[3]) + (s3[0] + s3[1] + s3[2] + s3[3]);
                float inv = 1.f / S;
                *(__bf16*)(wbuf + row * 512 + (((wv * 16 + llo) * 2) ^ ((row & 7) << 4))) =
                    (__bf16)(ee[rf][r] * inv);
            }
        __syncthreads();   // bar3: w visible

        // ---- Phase C: out[64x1024] = w @ V; wave owns d-cols [wv*64,+64) ----
        f32x4 acc2[4][4];
        #pragma unroll
        for (int rf = 0; rf < 4; ++rf)
            #pragma unroll
            for (int cf = 0; cf < 4; ++cf)
                acc2[rf][cf] = (f32x4){0.f, 0.f, 0.f, 0.f};

        #pragma unroll
        for (int cfh = 0; cfh < 2; ++cfh) {
            bf16x8 varr[2][8];
            const __bf16* vt0 = Vt + (size_t)l * D * NSUP
                              + (size_t)(wv * 64 + cfh * 32 + llo) * NSUP + lhi * 8;
            #pragma unroll
            for (int c2 = 0; c2 < 2; ++c2)
                #pragma unroll
                for (int k = 0; k < 8; ++k)
                    varr[c2][k] = *(const bf16x8*)(vt0 + (size_t)c2 * 16 * NSUP + k * 32);
            #pragma unroll
            for (int k = 0; k < 8; ++k) {
                bf16x8 a[4];
                #pragma unroll
                for (int rf = 0; rf < 4; ++rf)
                    a[rf] = *(const bf16x8*)(wbuf + (rf * 16 + llo) * 512 + ((k * 64 + lhi * 16) ^ swzk));
                #pragma unroll
                for (int c2 = 0; c2 < 2; ++c2)
                    #pragma unroll
                    for (int rf = 0; rf < 4; ++rf)
                        acc2[rf][cfh * 2 + c2] = MFMA16(a[rf], varr[c2][k], acc2[rf][cfh * 2 + c2]);
            }
        }

        if (l < 3) {
            // raw-h writeback (h reads all done at bar1; others only touch wbuf now)
            #pragma unroll
            for (int rf = 0; rf < 4; ++rf)
                #pragma unroll
                for (int cf = 0; cf < 4; ++cf)
                    #pragma unroll
                    for (int r = 0; r < 4; ++r) {
                        int row = rf * 16 + lhi * 4 + r;
                        int col = wv * 64 + cf * 16 + llo;
                        *(__bf16*)(pool + row * 2048 + ((col * 2) ^ ((row & 7) << 4))) =
                            (__bf16)acc2[rf][cf][r];
                    }
            // sq partials (kept in regs until next layer's A-start)
            #pragma unroll
            for (int rf = 0; rf < 4; ++rf)
                #pragma unroll
                for (int r = 0; r < 4; ++r) {
                    float s = 0.f;
                    #pragma unroll
                    for (int cf = 0; cf < 4; ++cf) s += acc2[rf][cf][r] * acc2[rf][cf][r];
                    s += __shfl_xor(s, 1); s += __shfl_xor(s, 2);
                    s += __shfl_xor(s, 4); s += __shfl_xor(s, 8);
                    sqp[rf][r] = s;
                }
            __syncthreads();   // bar4: h ready for next layer
        } else {
            // ---- final: LDS-staged f32 output, fully coalesced ----
            #pragma unroll 1
            for (int half = 0; half < 2; ++half) {
                #pragma unroll
                for (int rf2 = 0; rf2 < 2; ++rf2) {
                    int rf = half * 2 + rf2;
                    #pragma unroll
                    for (int cf = 0; cf < 4; ++cf)
                        #pragma unroll
                        for (int r = 0; r < 4; ++r) {
                            int row = rf * 16 + lhi * 4 + r;
                            int rowl = row - half * 32;
                            int col = wv * 64 + cf * 16 + llo;
                            *(float*)(pool + rowl * 4096 + ((col * 4) ^ ((rowl & 7) << 4))) =
                                acc2[rf][cf][r];
                        }
                }
                __syncthreads();
                #pragma unroll
                for (int i = 0; i < 8; ++i) {
                    int L = i * 16384 + tid * 16;
                    int rowl = L >> 12;
                    int off = L & 4095;
                    f32x4 v = *(const f32x4*)(pool + rowl * 4096 + (off ^ ((rowl & 7) << 4)));
                    *(f32x4*)((char*)(out + (size_t)(row0 + half * 32 + rowl) * D) + off) = v;
                }
                if (half == 0) __syncthreads();
            }
        }
    }
}

extern "C" void kernel_launch(void* const* d_in, const int* in_sizes, int n_in,
                              void* d_out, int out_size, void* d_ws, size_t ws_size,
                              hipStream_t stream) {
    const float* x = (const float*)d_in[0];
    const float* keys = (const float*)d_in[1];
    const float* values = (const float*)d_in[2];
    float* out = (float*)d_out;

    char* ws = (char*)d_ws;
    __bf16* Kb = (__bf16*)(ws);             // 4*256*1024*2 = 2 MB
    __bf16* Vt = (__bf16*)(ws + 2097152);   // 4*1024*256*2 = 2 MB

    (void)hipFuncSetAttribute((const void*)fused4_kernel,
                              hipFuncAttributeMaxDynamicSharedMemorySize, LDS_BYTES);

    cast_k_kernel<<<1024, 256, 0, stream>>>(keys, Kb);
    transpose_v_kernel<<<dim3(16, 4, 4), 256, 0, stream>>>(values, Vt);
    fused4_kernel<<<LGRID, LTHREADS, LDS_BYTES, stream>>>(x, out, Kb, Vt);
}

// Round 7
// 260.236 us; speedup vs baseline: 1.8961x; 1.8961x over previous
//
#include <hip/hip_runtime.h>
#include <hip/hip_bf16.h>
#include <stdint.h>

#define D 1024
#define NSUP 256
#define ROWS 16384      // 4*4096
#define MB 64           // rows per block
#define LTHREADS 1024   // 16 waves
#define LGRID (ROWS / MB)   // 256 blocks = 1/CU
#define LDS_BYTES 163840    // h 128K + wbuf 32K

typedef __attribute__((__ext_vector_type__(8))) __bf16 bf16x8;
typedef __attribute__((__ext_vector_type__(4))) float f32x4;

#define MFMA16(a, b, c) __builtin_amdgcn_mfma_f32_16x16x32_bf16((a), (b), (c), 0, 0, 0)

__global__ void cast_k_kernel(const float* __restrict__ K, __bf16* __restrict__ Kb) {
    int i = (blockIdx.x * 256 + threadIdx.x) * 4;
    float4 v = *(const float4*)(K + i);
    __bf16 o[4] __attribute__((aligned(8)));
    o[0] = (__bf16)v.x; o[1] = (__bf16)v.y; o[2] = (__bf16)v.z; o[3] = (__bf16)v.w;
    *(uint2*)(Kb + i) = *(const uint2*)o;
}

// V [4][256][1024] f32 -> Vt [4][1024][256] bf16
__global__ void transpose_v_kernel(const float* __restrict__ V, __bf16* __restrict__ Vt) {
    __shared__ __bf16 tile[64][72];
    int l = blockIdx.z;
    int d0 = blockIdx.x * 64, n0 = blockIdx.y * 64;
    const float* Vl = V + (size_t)l * NSUP * D;
    __bf16* Vtl = Vt + (size_t)l * D * NSUP;
    for (int j = 0; j < 16; ++j) {
        int idx = j * 256 + threadIdx.x;
        int n_l = idx >> 6, d_l = idx & 63;
        tile[d_l][n_l] = (__bf16)Vl[(size_t)(n0 + n_l) * D + d0 + d_l];
    }
    __syncthreads();
    for (int j = 0; j < 16; ++j) {
        int idx = j * 256 + threadIdx.x;
        int d_l = idx >> 6, n_l = idx & 63;
        Vtl[(size_t)(d0 + d_l) * NSUP + n0 + n_l] = tile[d_l][n_l];
    }
}

// All 4 layers fused, h resident in LDS (raw bf16, swizzled).
// Per layer: [sqp store | A-MFMA w/ K dbuf] bar1 [rn, exp, partials] bar2
// [S totals, w->wbuf] bar3 [C-MFMA w/ V dbuf, split in 2 col-halves |
//  h writeback (l<3) or direct f32 out (l=3)] bar4.
// No softmax max-pass: |score*rn| <= |k_row| ~ 34 -> exp2 arg <= 49, f32-safe.
// waves_per_eu(4,4): exactly 16 waves/CU -> 128-VGPR budget (compiler can't
// see the dynamic-LDS occupancy limit and would otherwise cap at 64 & spill).
__global__ void __launch_bounds__(LTHREADS) __attribute__((amdgpu_waves_per_eu(4, 4)))
fused4_kernel(const float* __restrict__ x, float* __restrict__ out,
              const __bf16* __restrict__ Kb, const __bf16* __restrict__ Vt) {
    extern __shared__ __align__(16) char pool[];
    char* wbuf = pool + 131072;
    const int tid = threadIdx.x;
    const int lane = tid & 63;
    const int wv = tid >> 6;            // wave 0..15
    const int llo = lane & 15, lhi = lane >> 4;
    const int swzk = (llo & 7) << 4;    // swizzle key for row = *16 + llo
    const int row0 = blockIdx.x * MB;

    // ---- stage x -> raw bf16 h (swizzled) + layer-0 rn ----
    {
        const int srow = tid >> 4, c16 = tid & 15;
        const float* xr = x + (size_t)(row0 + srow) * D;
        const int sk = (srow & 7) << 4;
        float ss = 0.f;
        #pragma unroll
        for (int q = 0; q < 16; ++q) {
            float4 v = *(const float4*)(xr + (c16 + q * 16) * 4);
            ss += v.x * v.x + v.y * v.y + v.z * v.z + v.w * v.w;
            __bf16 t[4] __attribute__((aligned(8)));
            t[0] = (__bf16)v.x; t[1] = (__bf16)v.y; t[2] = (__bf16)v.z; t[3] = (__bf16)v.w;
            *(uint2*)(pool + srow * 2048 + (((c16 + q * 16) * 8) ^ sk)) = *(const uint2*)t;
        }
        ss += __shfl_xor(ss, 1); ss += __shfl_xor(ss, 2);
        ss += __shfl_xor(ss, 4); ss += __shfl_xor(ss, 8);
        if (c16 == 0) *(float*)(wbuf + srow * 4) = 1.f / (sqrtf(ss) + 1e-9f);
    }
    __syncthreads();

    float sqp[4][4];   // prev-layer |row|^2 wave-partials (valid for l>0)

    #pragma unroll 1
    for (int l = 0; l < 4; ++l) {
        // ---- prev layer's sq-norm partials -> wbuf[0:4K) (wbuf dead here) ----
        if (l > 0) {
            #pragma unroll
            for (int rf = 0; rf < 4; ++rf)
                #pragma unroll
                for (int r = 0; r < 4; ++r)
                    if (llo == 0)
                        *(float*)(wbuf + (rf * 16 + lhi * 4 + r) * 64 + wv * 4) = sqp[rf][r];
        }

        // ---- Phase A: scores[64x256] = h @ K^T; wave owns cols [wv*16,+16) ----
        f32x4 acc[4];
        #pragma unroll
        for (int rf = 0; rf < 4; ++rf) acc[rf] = (f32x4){0.f, 0.f, 0.f, 0.f};
        const __bf16* kb0 = Kb + (size_t)l * NSUP * D + (size_t)(wv * 16 + llo) * D + lhi * 8;
        bf16x8 kbuf[2][4];
        #pragma unroll
        for (int j = 0; j < 4; ++j) kbuf[0][j] = *(const bf16x8*)(kb0 + j * 32);
        #pragma unroll
        for (int kc = 0; kc < 8; ++kc) {
            if (kc < 7) {
                #pragma unroll
                for (int j = 0; j < 4; ++j)
                    kbuf[(kc + 1) & 1][j] = *(const bf16x8*)(kb0 + ((kc + 1) * 4 + j) * 32);
            }
            #pragma unroll
            for (int j = 0; j < 4; ++j) {
                const int k = kc * 4 + j;
                #pragma unroll
                for (int rf = 0; rf < 4; ++rf) {
                    bf16x8 a = *(const bf16x8*)(pool + (rf * 16 + llo) * 2048
                                                + ((k * 64 + lhi * 16) ^ swzk));
                    acc[rf] = MFMA16(a, kbuf[kc & 1][j], acc[rf]);
                }
            }
        }
        __syncthreads();   // bar1: A done; h + wbuf partials readable

        // ---- rn for this layer ----
        float rnv[4][4];
        if (l == 0) {
            #pragma unroll
            for (int rf = 0; rf < 4; ++rf)
                #pragma unroll
                for (int r = 0; r < 4; ++r)
                    rnv[rf][r] = *(const float*)(wbuf + (rf * 16 + lhi * 4 + r) * 4);
        } else {
            #pragma unroll
            for (int rf = 0; rf < 4; ++rf)
                #pragma unroll
                for (int r = 0; r < 4; ++r) {
                    const f32x4* rp = (const f32x4*)(wbuf + (rf * 16 + lhi * 4 + r) * 64);
                    f32x4 s0 = rp[0], s1 = rp[1], s2 = rp[2], s3 = rp[3];
                    float ss = (s0[0] + s0[1] + s0[2] + s0[3]) + (s1[0] + s1[1] + s1[2] + s1[3])
                             + (s2[0] + s2[1] + s2[2] + s2[3]) + (s3[0] + s3[1] + s3[2] + s3[3]);
                    rnv[rf][r] = 1.f / (sqrtf(ss) + 1e-9f);
                }
        }

        // ---- exp (no max-sub) + partial sums -> pool[0:4K) (h rows 0-1 dead) ----
        float ee[4][4];
        #pragma unroll
        for (int rf = 0; rf < 4; ++rf)
            #pragma unroll
            for (int r = 0; r < 4; ++r) {
                float e = exp2f(acc[rf][r] * rnv[rf][r] * 1.44269504f);
                ee[rf][r] = e;
                float s = e;
                s += __shfl_xor(s, 1); s += __shfl_xor(s, 2);
                s += __shfl_xor(s, 4); s += __shfl_xor(s, 8);
                if (llo == 0) *(float*)(pool + (rf * 16 + lhi * 4 + r) * 64 + wv * 4) = s;
            }
        __syncthreads();   // bar2: exp partials visible

        #pragma unroll
        for (int rf = 0; rf < 4; ++rf)
            #pragma unroll
            for (int r = 0; r < 4; ++r) {
                int row = rf * 16 + lhi * 4 + r;
                const f32x4* rp = (const f32x4*)(pool + row * 64);
                f32x4 s0 = rp[0], s1 = rp[1], s2 = rp[2], s3 = rp[3];
                float S = (s0[0] + s0[1] + s0[2] + s0[3]) + (s1[0] + s1[1] + s1[2] + s1[3])
                        + (s2[0] + s2[1] + s2[2] + s2[3]) + (s3[0] + s3[1] + s3[2] + s3[3]);
                float inv = 1.f / S;
                *(__bf16*)(wbuf + row * 512 + (((wv * 16 + llo) * 2) ^ ((row & 7) << 4))) =
                    (__bf16)(ee[rf][r] * inv);
            }
        __syncthreads();   // bar3: w visible

        // ---- Phase C: out[64x1024] = w @ V; wave owns d-cols [wv*64,+64),
        //      processed as two 32-col halves to halve accumulator pressure ----
        float sql[4][4];
        #pragma unroll
        for (int rf = 0; rf < 4; ++rf)
            #pragma unroll
            for (int r = 0; r < 4; ++r) sql[rf][r] = 0.f;

        #pragma unroll 1
        for (int cfh = 0; cfh < 2; ++cfh) {
            f32x4 acc2[4][2];
            #pragma unroll
            for (int rf = 0; rf < 4; ++rf)
                #pragma unroll
                for (int c2 = 0; c2 < 2; ++c2)
                    acc2[rf][c2] = (f32x4){0.f, 0.f, 0.f, 0.f};
            const __bf16* vt0 = Vt + (size_t)l * D * NSUP
                              + (size_t)(wv * 64 + cfh * 32 + llo) * NSUP + lhi * 8;
            bf16x8 vbuf[2][2];
            #pragma unroll
            for (int c2 = 0; c2 < 2; ++c2)
                vbuf[0][c2] = *(const bf16x8*)(vt0 + (size_t)c2 * 16 * NSUP);
            #pragma unroll
            for (int k = 0; k < 8; ++k) {
                if (k < 7) {
                    #pragma unroll
                    for (int c2 = 0; c2 < 2; ++c2)
                        vbuf[(k + 1) & 1][c2] = *(const bf16x8*)(vt0 + (size_t)c2 * 16 * NSUP + (k + 1) * 32);
                }
                bf16x8 a[4];
                #pragma unroll
                for (int rf = 0; rf < 4; ++rf)
                    a[rf] = *(const bf16x8*)(wbuf + (rf * 16 + llo) * 512
                                             + ((k * 64 + lhi * 16) ^ swzk));
                #pragma unroll
                for (int c2 = 0; c2 < 2; ++c2)
                    #pragma unroll
                    for (int rf = 0; rf < 4; ++rf)
                        acc2[rf][c2] = MFMA16(a[rf], vbuf[k & 1][c2], acc2[rf][c2]);
            }
            if (l < 3) {
                // raw-h writeback for these 32 cols + sq accumulation
                #pragma unroll
                for (int rf = 0; rf < 4; ++rf)
                    #pragma unroll
                    for (int c2 = 0; c2 < 2; ++c2)
                        #pragma unroll
                        for (int r = 0; r < 4; ++r) {
                            int row = rf * 16 + lhi * 4 + r;
                            int col = wv * 64 + cfh * 32 + c2 * 16 + llo;
                            float v = acc2[rf][c2][r];
                            *(__bf16*)(pool + row * 2048 + ((col * 2) ^ ((row & 7) << 4))) = (__bf16)v;
                            sql[rf][r] += v * v;
                        }
            } else {
                // final: direct f32 stores (16-lane x 4B = 64B dense runs)
                #pragma unroll
                for (int rf = 0; rf < 4; ++rf)
                    #pragma unroll
                    for (int c2 = 0; c2 < 2; ++c2)
                        #pragma unroll
                        for (int r = 0; r < 4; ++r) {
                            int row = rf * 16 + lhi * 4 + r;
                            int col = wv * 64 + cfh * 32 + c2 * 16 + llo;
                            out[(size_t)(row0 + row) * D + col] = acc2[rf][c2][r];
                        }
            }
        }

        if (l < 3) {
            #pragma unroll
            for (int rf = 0; rf < 4; ++rf)
                #pragma unroll
                for (int r = 0; r < 4; ++r) {
                    float s = sql[rf][r];
                    s += __shfl_xor(s, 1); s += __shfl_xor(s, 2);
                    s += __shfl_xor(s, 4); s += __shfl_xor(s, 8);
                    sqp[rf][r] = s;
                }
            __syncthreads();   // bar4: h ready for next layer
        }
    }
}

extern "C" void kernel_launch(void* const* d_in, const int* in_sizes, int n_in,
                              void* d_out, int out_size, void* d_ws, size_t ws_size,
                              hipStream_t stream) {
    const float* x = (const float*)d_in[0];
    const float* keys = (const float*)d_in[1];
    const float* values = (const float*)d_in[2];
    float* out = (float*)d_out;

    char* ws = (char*)d_ws;
    __bf16* Kb = (__bf16*)(ws);             // 4*256*1024*2 = 2 MB
    __bf16* Vt = (__bf16*)(ws + 2097152);   // 4*1024*256*2 = 2 MB

    (void)hipFuncSetAttribute((const void*)fused4_kernel,
                              hipFuncAttributeMaxDynamicSharedMemorySize, LDS_BYTES);

    cast_k_kernel<<<1024, 256, 0, stream>>>(keys, Kb);
    transpose_v_kernel<<<dim3(16, 4, 4), 256, 0, stream>>>(values, Vt);
    fused4_kernel<<<LGRID, LTHREADS, LDS_BYTES, stream>>>(x, out, Kb, Vt);
}